// Round 11
// baseline (2532821.680 us; speedup 1.0000x reference)
//
#include <hip/hip_runtime.h>
#include <hip/hip_cooperative_groups.h>

namespace cg = cooperative_groups;

typedef _Float16 f16;
typedef _Float16 half8 __attribute__((ext_vector_type(8)));
typedef float float4v __attribute__((ext_vector_type(4)));
typedef int int4v __attribute__((ext_vector_type(4)));
typedef unsigned long long u64;

constexpr int kB  = 512;   // batch
constexpr int kT  = 512;   // seq len
constexpr int kI  = 128;   // input dim
constexpr int kH  = 512;   // hidden
constexpr int kNG = 2048;  // 4*H
constexpr int kO  = 128;   // output dim

// Padded K-stride (f16) for resident W in LDS; conflict-free b128 (verified R5).
constexpr int LDK = 650;

__device__ __forceinline__ float fsig(float v)  { return 1.0f / (1.0f + __expf(-v)); }
__device__ __forceinline__ float ftanh(float v) { return 1.0f - 2.0f / (1.0f + __expf(2.0f * v)); }

union h8u { half8 h; int4v i; u64 u[2]; };
union f16u { f16 f; unsigned short s; };

// 256 WGs x 256 threads, cooperative. LDS (83KB) forces 1 WG/CU; a successful
// 256-WG cooperative launch => WG<->CU bijection (pigeonhole) => exactly 32
// WGs per XCD. bg = physical XCC_ID, ng = per-XCD ticket.
// FAST path: h exchange entirely in the XCD-local L2 (plain stores write
// through vL1 -> L2; sc0 loads bypass stale L1, read local L2). Flag barrier
// on same-L2 lines. FALLBACK (ticket counts != 32, should be impossible):
// R7-proven sc1/IF$ protocol. Liveness: sc0 poll capped, then sc1 mirror.
// R10 -> R11 fix: restore __syncthreads() between W staging and first w_lds
// read (R10's NaN: xacc(0) MFMA raced the staging loop).
__global__ __launch_bounds__(256, 1) void lstm_fused(
    const float* __restrict__ x,  const float* __restrict__ Wx,
    const float* __restrict__ Wh, const float* __restrict__ bias,
    const float* __restrict__ Wp, const float* __restrict__ bp,
    float* __restrict__ out, float* __restrict__ ws)
{
  cg::grid_group grid = cg::this_grid();

  __shared__ __align__(16) f16 w_lds[64 * LDK];
  __shared__ unsigned s_ng;

  const int tid = threadIdx.x;
  const int wg  = blockIdx.x;
  const int wv  = tid >> 6;     // wave 0..3
  const int l   = tid & 63;
  const int lc  = l & 15;       // fragment row/col
  const int lj  = l >> 4;       // k-group 0..3

  f16* h16a = (f16*)ws;                          // [512][512] fp16
  f16* h16b = h16a + kB * kH;
  unsigned* flags = (unsigned*)(h16b + kB * kH); // 256 slots x 128B (sc0, L2-local)
  unsigned* tcnt  = flags + 8192;                // 8 counters x 128B spacing
  unsigned* mirr  = flags + 8448;                // 256 mirror slots x 128B (sc1, IF$)

  // ---- init: zero h0 + entire sync area (ws poisoned; re-init every call) ----
  {
    int gtid = wg * 256 + tid;                 // 65536 threads
    unsigned* p = (unsigned*)h16a;             // 131072 u32 = 512 KB
    p[gtid * 2] = 0u; p[gtid * 2 + 1] = 0u;
    if (gtid < 16640) flags[gtid] = 0u;        // flags + tcnt + mirrors
  }

  grid.sync();   // zeros globally visible (release wbl2 / acquire inv)

  // ---- ticket within physical XCD ----
  unsigned xcd;
  asm volatile("s_getreg_b32 %0, hwreg(HW_REG_XCC_ID)" : "=s"(xcd));
  xcd &= 7u;
  if (tid == 0)
    s_ng = __hip_atomic_fetch_add(&tcnt[xcd * 32], 1u,
             __ATOMIC_RELAXED, __HIP_MEMORY_SCOPE_AGENT);
  __syncthreads();
  const unsigned ticket = s_ng;

  grid.sync();   // all tickets taken

  // ---- verify bijection; decide protocol (uniform across grid) ----
  bool fast = true;
  #pragma unroll
  for (int i = 0; i < 8; ++i) {
    unsigned c = __hip_atomic_load(&tcnt[i * 32], __ATOMIC_RELAXED, __HIP_MEMORY_SCOPE_AGENT);
    fast = fast && (c == 32u);
  }
  const int bg = fast ? (int)xcd : (wg & 7);
  const int ng = fast ? (int)(ticket & 31u) : (wg >> 3);
  const int b0 = bg * 64;

  // ---- one-time: stage W slice -> LDS fp16 (cols for this ng) ----
  for (int idx = tid; idx < 64 * 640; idx += 256) {
    int c = idx & 63;
    int k = idx >> 6;
    int gcol = (c >> 4) * 512 + ng * 16 + (c & 15);
    float v = (k < 512) ? Wh[(long)k * kNG + gcol]
                        : Wx[(long)(k - 512) * kNG + gcol];
    w_lds[c * LDK + k] = (f16)v;
  }
  __syncthreads();   // *** R11 FIX: w_lds fully staged before ANY read below ***

  float bb[4];
  #pragma unroll
  for (int g = 0; g < 4; ++g) bb[g] = bias[g * 512 + ng * 16 + lc];

  float ce[4] = {0.f, 0.f, 0.f, 0.f};
  const int arow = b0 + wv * 16 + lc;
  const f16* wbase = w_lds + lc * LDK + lj * 8;
  const float* xrow = x + (long)arow * (kT * kI) + lj * 8;

  // flag hygiene: each WG sc0-zeroes its group's 32 slots THROUGH ITS OWN L2
  // (kills any stale local line; redundant across the group, same value)
  if (tid < 32) {
    unsigned zoff = (unsigned)((bg * 32 + tid) * 128);
    unsigned z = 0u;
    asm volatile("global_store_dword %0, %1, %2 sc0"
                 :: "v"(zoff), "v"(z), "s"(flags) : "memory");
  }

  // x(0) load + xacc(0) = bias + x(0)@Wx, then prefetch x(1)
  float4v xa[4], xb[4];
  #pragma unroll
  for (int q = 0; q < 4; ++q) {
    xa[q] = *(const float4v*)(xrow + q * 32);
    xb[q] = *(const float4v*)(xrow + q * 32 + 4);
  }
  float4v xacc[4];
  #pragma unroll
  for (int g = 0; g < 4; ++g) xacc[g] = float4v{bb[g], bb[g], bb[g], bb[g]};
  #pragma unroll
  for (int q = 0; q < 4; ++q) {
    half8 a;
    #pragma unroll
    for (int e = 0; e < 4; ++e) { a[e] = (f16)xa[q][e]; a[e + 4] = (f16)xb[q][e]; }
    #pragma unroll
    for (int g = 0; g < 4; ++g) {
      half8 bf = *(const half8*)(wbase + g * 16 * LDK + 512 + q * 32);
      xacc[g] = __builtin_amdgcn_mfma_f32_16x16x32_f16(a, bf, xacc[g], 0, 0, 0);
    }
  }
  #pragma unroll
  for (int q = 0; q < 4; ++q) {
    xa[q] = *(const float4v*)(xrow + kI + q * 32);
    xb[q] = *(const float4v*)(xrow + kI + q * 32 + 4);
  }

  const unsigned hoff = (unsigned)(arow * kH * 2 + lj * 16);    // lane frag base (bytes)
  const unsigned foff = (unsigned)((bg * 32 + ng) * 128);       // my flag slot (bytes)
  const unsigned poff = (unsigned)((bg * 32 + (l & 31)) * 128); // lane's poll slot (bytes)
  unsigned* mslot = mirr + (bg * 32 + ng) * 32;
  const unsigned* mpoll = mirr + (bg * 32 + (l & 31)) * 32;

  grid.sync();   // flag hygiene + h zeros settled everywhere

  for (int t = 0; t < kT; ++t) {
    const f16* hc = (t & 1) ? h16b : h16a;
    f16*       hn = (t & 1) ? h16a : h16b;

    // ---- h loads ----
    h8u ah[16];
    if (fast) {
      // sc0: bypass stale L1, read XCD-local L2. Fragment p = bytes [p*64, p*64+16).
      #pragma unroll
      for (int p = 0; p < 16; ++p) {
        asm volatile("global_load_dwordx4 %0, %1, %2 offset:%c3 sc0"
                     : "=v"(ah[p].i)
                     : "v"(hoff), "s"(hc), "i"(p * 64));
      }
      asm volatile("s_waitcnt vmcnt(0)" ::: "memory");
      __builtin_amdgcn_sched_barrier(0);
    } else {
      const u64* hp64 = (const u64*)hc + (long)arow * 128 + lj * 2;
      #pragma unroll
      for (int p = 0; p < 16; ++p) {
        ah[p].u[0] = __hip_atomic_load(hp64 + p * 8,     __ATOMIC_RELAXED, __HIP_MEMORY_SCOPE_AGENT);
        ah[p].u[1] = __hip_atomic_load(hp64 + p * 8 + 1, __ATOMIC_RELAXED, __HIP_MEMORY_SCOPE_AGENT);
      }
    }

    // z = xacc(t) + h@Wh
    float4v acc[4];
    #pragma unroll
    for (int g = 0; g < 4; ++g) acc[g] = xacc[g];
    #pragma unroll
    for (int ks = 0; ks < 16; ++ks) {
      #pragma unroll
      for (int g = 0; g < 4; ++g) {
        half8 bf = *(const half8*)(wbase + g * 16 * LDK + ks * 32);
        acc[g] = __builtin_amdgcn_mfma_f32_16x16x32_f16(ah[ks].h, bf, acc[g], 0, 0, 0);
      }
    }

    // gate update in registers
    unsigned short hv[4];
    #pragma unroll
    for (int e = 0; e < 4; ++e) {
      float gv = ftanh(acc[0][e]);
      float iv = fsig(acc[1][e]);
      float fv = fsig(acc[2][e]);
      float ov = fsig(acc[3][e]);
      float cn = gv * iv + ce[e] * fv;
      ce[e] = cn;
      f16u u; u.f = (f16)(ftanh(cn) * ov);
      hv[e] = u.s;
    }
    {
      unsigned short* dst = (unsigned short*)hn + (long)(b0 + wv * 16 + lj * 4) * kH + ng * 16 + lc;
      if (fast) {
        #pragma unroll
        for (int e = 0; e < 4; ++e) dst[(long)e * kH] = hv[e];   // plain: vL1 write-through -> local L2
      } else {
        #pragma unroll
        for (int e = 0; e < 4; ++e)
          __hip_atomic_store(dst + (long)e * kH, hv[e], __ATOMIC_RELAXED, __HIP_MEMORY_SCOPE_AGENT);
      }
    }

    // ---- group barrier ----
    // __syncthreads drains vmcnt(0) per wave => all h stores are in L2 (fast)
    // or at IF$ (fallback) before tid0 publishes.
    __syncthreads();
    if (tid == 0) {
      unsigned val = (unsigned)(t + 1);
      asm volatile("global_store_dword %0, %1, %2 sc0"
                   :: "v"(foff), "v"(val), "s"(flags) : "memory");
      __hip_atomic_store(mslot, val, __ATOMIC_RELAXED, __HIP_MEMORY_SCOPE_AGENT);  // sc1 mirror (liveness)
    }

    // wait shadow: xacc(t+1) = bias + x(t+1)@Wx (h-independent), x(t+2) prefetch
    if (t + 1 < kT) {
      #pragma unroll
      for (int g = 0; g < 4; ++g) xacc[g] = float4v{bb[g], bb[g], bb[g], bb[g]};
      #pragma unroll
      for (int q = 0; q < 4; ++q) {
        half8 a;
        #pragma unroll
        for (int e = 0; e < 4; ++e) { a[e] = (f16)xa[q][e]; a[e + 4] = (f16)xb[q][e]; }
        #pragma unroll
        for (int g = 0; g < 4; ++g) {
          half8 bf = *(const half8*)(wbase + g * 16 * LDK + 512 + q * 32);
          xacc[g] = __builtin_amdgcn_mfma_f32_16x16x32_f16(a, bf, xacc[g], 0, 0, 0);
        }
      }
      if (t + 2 < kT) {
        const float* xn = xrow + (long)(t + 2) * kI;
        #pragma unroll
        for (int q = 0; q < 4; ++q) {
          xa[q] = *(const float4v*)(xn + q * 32);
          xb[q] = *(const float4v*)(xn + q * 32 + 4);
        }
      }
    }

    // wave-parallel poll: lane i watches slot (i&31). Fast: sc0 (local L2),
    // capped spins -> sc1 mirror (bounded liveness). Fallback: mirror only.
    if (wv == 0) {
      const unsigned tgt = (unsigned)(t + 1);
      if (fast) {
        unsigned v, spins = 0; bool done = false;
        do {
          asm volatile("global_load_dword %0, %1, %2 sc0\n\ts_waitcnt vmcnt(0)"
                       : "=v"(v) : "v"(poff), "s"(flags) : "memory");
          done = (__all((int)(v >= tgt)) != 0);
          if (!done && ++spins > 65536u) {
            do {
              v = __hip_atomic_load(mpoll, __ATOMIC_RELAXED, __HIP_MEMORY_SCOPE_AGENT);
            } while (__all((int)(v >= tgt)) == 0);
            done = true;
          }
        } while (!done);
      } else {
        unsigned v;
        do {
          v = __hip_atomic_load(mpoll, __ATOMIC_RELAXED, __HIP_MEMORY_SCOPE_AGENT);
        } while (__all((int)(v >= tgt)) == 0);
      }
    }
    __syncthreads();
  }

  grid.sync();   // release: all dirty h written back; acquire: L1/L2 inv'd

  // ---- projection + softmax: rows wg*2, wg*2+1 (final h in h16a) ----
  const f16* hf = h16a;
  float* hrow = (float*)w_lds;             // reuse LDS
  float* red  = (float*)w_lds + 2 * kH;
  for (int i = tid; i < 2 * kH; i += 256) {
    int r = i >> 9, k = i & 511;
    hrow[i] = (float)hf[(long)(wg * 2 + r) * kH + k];
  }
  __syncthreads();

  const int orow = tid >> 7;   // 0..1
  const int oc   = tid & 127;  // 0..127
  float p = bp[oc];
  #pragma unroll 8
  for (int k = 0; k < kH; ++k)
    p += hrow[orow * kH + k] * Wp[(long)k * kO + oc];

  red[tid] = p;
  __syncthreads();
  float m = -1e30f;
  for (int j = 0; j < 128; ++j) m = fmaxf(m, red[orow * 128 + j]);
  __syncthreads();
  float e = __expf(p - m);
  red[tid] = e;
  __syncthreads();
  float s = 0.f;
  for (int j = 0; j < 128; ++j) s += red[orow * 128 + j];
  out[(long)(wg * 2 + orow) * kO + oc] = e / s;
}

extern "C" void kernel_launch(void* const* d_in, const int* in_sizes, int n_in,
                              void* d_out, int out_size, void* d_ws, size_t ws_size,
                              hipStream_t stream) {
  const float* x  = (const float*)d_in[0];
  const float* Wx = (const float*)d_in[1];
  const float* Wh = (const float*)d_in[2];
  const float* b  = (const float*)d_in[3];
  const float* Wp = (const float*)d_in[4];
  const float* bp = (const float*)d_in[5];
  float* out = (float*)d_out;
  float* ws  = (float*)d_ws;

  void* args[] = { &x, &Wx, &Wh, &b, &Wp, &bp, &out, &ws };
  hipLaunchCooperativeKernel((void*)lstm_fused, dim3(256), dim3(256), args, 0, stream);
}

// Round 13
// 6124.778 us; speedup vs baseline: 413.5369x; 413.5369x over previous
//
#include <hip/hip_runtime.h>
#include <hip/hip_cooperative_groups.h>

namespace cg = cooperative_groups;

typedef _Float16 f16;
typedef _Float16 half8 __attribute__((ext_vector_type(8)));
typedef float float4v __attribute__((ext_vector_type(4)));
typedef int int4v __attribute__((ext_vector_type(4)));

constexpr int kB  = 512;   // batch
constexpr int kT  = 512;   // seq len
constexpr int kI  = 128;   // input dim
constexpr int kH  = 512;   // hidden
constexpr int kNG = 2048;  // 4*H
constexpr int kO  = 128;   // output dim

// Padded K-stride (f16) for resident W in LDS; conflict-free b128 (verified R5).
constexpr int LDK = 650;

__device__ __forceinline__ float fsig(float v)  { return 1.0f / (1.0f + __expf(-v)); }
__device__ __forceinline__ float ftanh(float v) { return 1.0f - 2.0f / (1.0f + __expf(2.0f * v)); }

union h8u { half8 h; int4v i; };   // aggregate: no ctor (R12's host-only ctor broke device init)
union f16u { f16 f; unsigned short s; };

// 256 WGs x 256 threads, cooperative (co-residency for spin barriers + 2
// one-time grid syncs). WG: bg = blockIdx&7 (64 batch rows), ng = blockIdx>>3
// (16 h-cols). All h/flag exchange via sc1 (IF$ coherence point) -- the ONLY
// propagation path proven live (R6/R7; R11: sc0-only flags stay stale >65536
// spins, sc1 mirror releases).
// R13 == R12 theory: WAVE-AUTONOMOUS barrier. Per-wave flags [bg][ng][wv];
// each wave: h stores (sc1) -> s_waitcnt vmcnt(0) -> lane0 publishes own flag
// -> xacc shadow -> poll all 128 group slots (2/lane). Zero __syncthreads in
// the loop: removes 2 s_barriers + slowest-wave-in-WG publish serialization.
__global__ __launch_bounds__(256, 1) void lstm_fused(
    const float* __restrict__ x,  const float* __restrict__ Wx,
    const float* __restrict__ Wh, const float* __restrict__ bias,
    const float* __restrict__ Wp, const float* __restrict__ bp,
    float* __restrict__ out, float* __restrict__ ws)
{
  cg::grid_group grid = cg::this_grid();

  __shared__ __align__(16) f16 w_lds[64 * LDK];

  const int tid = threadIdx.x;
  const int wg  = blockIdx.x;
  const int bg  = wg & 7;
  const int ng  = wg >> 3;
  const int b0  = bg * 64;
  const int wv  = tid >> 6;     // wave 0..3
  const int l   = tid & 63;
  const int lc  = l & 15;       // fragment row/col
  const int lj  = l >> 4;       // k-group 0..3

  f16* h16a = (f16*)ws;                          // [512][512] fp16
  f16* h16b = h16a + kB * kH;
  // per-wave flags: (bg*32+ng)*4+wv, 128B spacing -> 1024 slots, 128 KB
  unsigned* flags = (unsigned*)(h16b + kB * kH);

  // ---- init: zero h0 + flag area (ws poisoned; re-init every call) ----
  {
    int gtid = wg * 256 + tid;                 // 65536 threads
    unsigned* p = (unsigned*)h16a;             // 131072 u32 = 512 KB
    p[gtid * 2] = 0u; p[gtid * 2 + 1] = 0u;
    if (gtid < 32768) flags[gtid] = 0u;        // 128 KB flag region
  }

  // ---- one-time: stage W slice -> LDS fp16 ----
  for (int idx = tid; idx < 64 * 640; idx += 256) {
    int c = idx & 63;
    int k = idx >> 6;
    int gcol = (c >> 4) * 512 + ng * 16 + (c & 15);
    float v = (k < 512) ? Wh[(long)k * kNG + gcol]
                        : Wx[(long)(k - 512) * kNG + gcol];
    w_lds[c * LDK + k] = (f16)v;
  }
  float bb[4];
  #pragma unroll
  for (int g = 0; g < 4; ++g) bb[g] = bias[g * 512 + ng * 16 + lc];

  float ce[4] = {0.f, 0.f, 0.f, 0.f};
  const int arow = b0 + wv * 16 + lc;
  const f16* wbase = w_lds + lc * LDK + lj * 8;
  const float* xrow = x + (long)arow * (kT * kI) + lj * 8;

  // preload x(0) (hides L3 latency under the grid sync)
  float4v xa[4], xb[4];
  #pragma unroll
  for (int q = 0; q < 4; ++q) {
    xa[q] = *(const float4v*)(xrow + q * 32);
    xb[q] = *(const float4v*)(xrow + q * 32 + 4);
  }

  grid.sync();   // h zeros + flag zeros globally visible; w_lds staged (WG-wide)

  // my publish slot; poll slots: lane covers (ng'=l&31, wv' = l>>5 and (l>>5)+2)
  unsigned* myslot = flags + (((unsigned)(bg * 32 + ng) * 4u + (unsigned)wv) * 32u);
  const unsigned* poll0 = flags + (((unsigned)(bg * 32 + (l & 31)) * 4u + (unsigned)(l >> 5)) * 32u);
  const unsigned* poll1 = flags + (((unsigned)(bg * 32 + (l & 31)) * 4u + (unsigned)((l >> 5) + 2)) * 32u);

  // xacc(0) = bias + x(0)@Wx ; then prefetch x(1)
  float4v xacc[4];
  #pragma unroll
  for (int g = 0; g < 4; ++g) xacc[g] = float4v{bb[g], bb[g], bb[g], bb[g]};
  #pragma unroll
  for (int q = 0; q < 4; ++q) {
    half8 a;
    #pragma unroll
    for (int e = 0; e < 4; ++e) { a[e] = (f16)xa[q][e]; a[e + 4] = (f16)xb[q][e]; }
    #pragma unroll
    for (int g = 0; g < 4; ++g) {
      half8 bf = *(const half8*)(wbase + g * 16 * LDK + 512 + q * 32);
      xacc[g] = __builtin_amdgcn_mfma_f32_16x16x32_f16(a, bf, xacc[g], 0, 0, 0);
    }
  }
  #pragma unroll
  for (int q = 0; q < 4; ++q) {
    xa[q] = *(const float4v*)(xrow + kI + q * 32);
    xb[q] = *(const float4v*)(xrow + kI + q * 32 + 4);
  }

  const unsigned hoff = (unsigned)(arow * kH * 2 + lj * 16);  // lane frag base (bytes)

  for (int t = 0; t < kT; ++t) {
    const f16* hc = (t & 1) ? h16b : h16a;
    f16*       hn = (t & 1) ? h16a : h16b;

    // h loads: 16 x dwordx4, sc0 sc1 = agent scope (read at IF$, the proven
    // coherence point). Fragment p = bytes [p*64, p*64+16).
    h8u ah[16];
    #pragma unroll
    for (int p = 0; p < 16; ++p) {
      asm volatile("global_load_dwordx4 %0, %1, %2 offset:%c3 sc0 sc1"
                   : "=v"(ah[p].i)
                   : "v"(hoff), "s"(hc), "i"(p * 64));
    }
    asm volatile("s_waitcnt vmcnt(0)" ::: "memory");
    __builtin_amdgcn_sched_barrier(0);

    // z = xacc(t) + h@Wh
    float4v acc[4];
    #pragma unroll
    for (int g = 0; g < 4; ++g) acc[g] = xacc[g];
    #pragma unroll
    for (int ks = 0; ks < 16; ++ks) {
      #pragma unroll
      for (int g = 0; g < 4; ++g) {
        half8 bf = *(const half8*)(wbase + g * 16 * LDK + ks * 32);
        acc[g] = __builtin_amdgcn_mfma_f32_16x16x32_f16(ah[ks].h, bf, acc[g], 0, 0, 0);
      }
    }

    // gate update in registers; h stores via relaxed agent atomics (sc1)
    #pragma unroll
    for (int e = 0; e < 4; ++e) {
      float gv = ftanh(acc[0][e]);
      float iv = fsig(acc[1][e]);
      float fv = fsig(acc[2][e]);
      float ov = fsig(acc[3][e]);
      float cn = gv * iv + ce[e] * fv;
      ce[e] = cn;
      f16u u; u.f = (f16)(ftanh(cn) * ov);
      unsigned short* dst = (unsigned short*)hn
          + (long)(b0 + wv * 16 + lj * 4 + e) * kH + ng * 16 + lc;
      __hip_atomic_store(dst, u.s, __ATOMIC_RELAXED, __HIP_MEMORY_SCOPE_AGENT);
    }

    // ---- wave-autonomous publish ----
    // drain THIS wave's sc1 h-stores to the IF$ coherence point, then publish.
    asm volatile("s_waitcnt vmcnt(0)" ::: "memory");
    if (l == 0)
      __hip_atomic_store(myslot, (unsigned)(t + 1), __ATOMIC_RELAXED, __HIP_MEMORY_SCOPE_AGENT);

    // wait shadow: xacc(t+1) = bias + x(t+1)@Wx (h-independent), x(t+2) prefetch
    if (t + 1 < kT) {
      #pragma unroll
      for (int g = 0; g < 4; ++g) xacc[g] = float4v{bb[g], bb[g], bb[g], bb[g]};
      #pragma unroll
      for (int q = 0; q < 4; ++q) {
        half8 a;
        #pragma unroll
        for (int e = 0; e < 4; ++e) { a[e] = (f16)xa[q][e]; a[e + 4] = (f16)xb[q][e]; }
        #pragma unroll
        for (int g = 0; g < 4; ++g) {
          half8 bf = *(const half8*)(wbase + g * 16 * LDK + 512 + q * 32);
          xacc[g] = __builtin_amdgcn_mfma_f32_16x16x32_f16(a, bf, xacc[g], 0, 0, 0);
        }
      }
      if (t + 2 < kT) {
        const float* xn = xrow + (long)(t + 2) * kI;
        #pragma unroll
        for (int q = 0; q < 4; ++q) {
          xa[q] = *(const float4v*)(xn + q * 32);
          xb[q] = *(const float4v*)(xn + q * 32 + 4);
        }
      }
    }

    // per-wave poll: 128 slots (32 ng x 4 waves), 2 per lane, relaxed sc1
    {
      const unsigned tgt = (unsigned)(t + 1);
      unsigned v0, v1;
      do {
        v0 = __hip_atomic_load(poll0, __ATOMIC_RELAXED, __HIP_MEMORY_SCOPE_AGENT);
        v1 = __hip_atomic_load(poll1, __ATOMIC_RELAXED, __HIP_MEMORY_SCOPE_AGENT);
        v0 = (v0 < v1) ? v0 : v1;
      } while (__all((int)(v0 >= tgt)) == 0);
    }
  }

  grid.sync();   // all groups done before cross-group projection reads

  // ---- projection + softmax: rows wg*2, wg*2+1 (final h in h16a) ----
  const f16* hf = h16a;
  float* hrow = (float*)w_lds;             // reuse LDS
  float* red  = (float*)w_lds + 2 * kH;
  for (int i = tid; i < 2 * kH; i += 256) {
    int r = i >> 9, k = i & 511;
    hrow[i] = (float)hf[(long)(wg * 2 + r) * kH + k];
  }
  __syncthreads();

  const int orow = tid >> 7;   // 0..1
  const int oc   = tid & 127;  // 0..127
  float p = bp[oc];
  #pragma unroll 8
  for (int k = 0; k < kH; ++k)
    p += hrow[orow * kH + k] * Wp[(long)k * kO + oc];

  red[tid] = p;
  __syncthreads();
  float m = -1e30f;
  for (int j = 0; j < 128; ++j) m = fmaxf(m, red[orow * 128 + j]);
  __syncthreads();
  float e = __expf(p - m);
  red[tid] = e;
  __syncthreads();
  float s = 0.f;
  for (int j = 0; j < 128; ++j) s += red[orow * 128 + j];
  out[(long)(wg * 2 + orow) * kO + oc] = e / s;
}

extern "C" void kernel_launch(void* const* d_in, const int* in_sizes, int n_in,
                              void* d_out, int out_size, void* d_ws, size_t ws_size,
                              hipStream_t stream) {
  const float* x  = (const float*)d_in[0];
  const float* Wx = (const float*)d_in[1];
  const float* Wh = (const float*)d_in[2];
  const float* b  = (const float*)d_in[3];
  const float* Wp = (const float*)d_in[4];
  const float* bp = (const float*)d_in[5];
  float* out = (float*)d_out;
  float* ws  = (float*)d_ws;

  void* args[] = { &x, &Wx, &Wh, &b, &Wp, &bp, &out, &ws };
  hipLaunchCooperativeKernel((void*)lstm_fused, dim3(256), dim3(256), args, 0, stream);
}